// Round 1
// 457.270 us; speedup vs baseline: 1.1865x; 1.1865x over previous
//
#include <hip/hip_runtime.h>
#include <hip/hip_bf16.h>
#include <stdint.h>

// BinaryTreeLSTM on MI355X (gfx950) — round 8.
// R7 measured: tail_kernel 170us at MfmaUtil 1.8% / VALUBusy 4.3% — pure
// latency from 6 grid-barrier phases + per-phase global h/c round-trips.
// R8: tree recursion is batch-local, so the tail needs NO grid barriers.
// New tail: 256 blocks = 1 batch element each; levels d=5..0 + classifier
// run block-locally with __syncthreads only. prev/cur h (bf16, XOR-swizzled)
// and c (fp32, stride-132 padded) live in LDS; x-frags hoisted to registers
// per level; B (weights) re-staged per k-step via the proven global_load_lds
// 1KB-chunk double buffer, full j=128 (40 chunks/step). LDS 157184B, 1 blk/CU.
// Levels d=9..6 and pack_w untouched (attack next round with their counters).

#define BATCH 256
#define NTOT 1023
#define HDIM 128
#define NCLS 5
#define GDIM 384

typedef __bf16 bf16x8 __attribute__((ext_vector_type(8)));
typedef float f32x4 __attribute__((ext_vector_type(4)));

__device__ __forceinline__ float sigmoid_f(float v) { return 1.f / (1.f + __expf(-v)); }
__device__ __forceinline__ float tanh_f(float v) { return 1.f - 2.f / (1.f + __expf(2.f * v)); }

__device__ __forceinline__ void load_lds16(const void* g, void* l) {
  __builtin_amdgcn_global_load_lds((const __attribute__((address_space(1))) unsigned int*)g,
                                   (__attribute__((address_space(3))) unsigned int*)l, 16, 0, 0);
}

// PW: 480 chunks of 1KB. chunk = (g*8 + jf)*12 + ks; lane l holds
// W[g][jf*16 + (l&15)][ks*32 + (l>>4)*8 + i], i=0..7  (16x16x32 b-frag order)
__global__ __launch_bounds__(256) void pack_w(
    const float* __restrict__ W0, const float* __restrict__ W1, const float* __restrict__ W2,
    const float* __restrict__ W3, const float* __restrict__ W4, __bf16* __restrict__ PW)
{
  int t = blockIdx.x * 256 + threadIdx.x;   // 30720
  int lane = t & 63;
  int chunk = t >> 6;
  int ks = chunk % 12;
  int jf = (chunk / 12) & 7;
  int g = chunk / 96;
  const float* W = (g == 0) ? W0 : (g == 1) ? W1 : (g == 2) ? W2 : (g == 3) ? W3 : W4;
  const float* s = W + (size_t)(jf * 16 + (lane & 15)) * GDIM + ks * 32 + (lane >> 4) * 8;
  float4 v0 = *(const float4*)s;
  float4 v1 = *(const float4*)(s + 4);
  bf16x8 w;
  w[0] = (__bf16)v0.x; w[1] = (__bf16)v0.y; w[2] = (__bf16)v0.z; w[3] = (__bf16)v0.w;
  w[4] = (__bf16)v1.x; w[5] = (__bf16)v1.y; w[6] = (__bf16)v1.z; w[7] = (__bf16)v1.w;
  *(bf16x8*)(PW + (size_t)t * 8) = w;
}

// One 64m x 64j x 5g tile. LDS per buffer: A 4KB (4 chunks) + B 20KB (20 chunks).
template<bool LEAF>
__device__ __forceinline__ void tile_body(
    const float* __restrict__ x, const __bf16* __restrict__ PW,
    const __bf16* __restrict__ h_prev, const float* __restrict__ c_prev,
    __bf16* __restrict__ h_out, float* __restrict__ c_out,
    const float* __restrict__ bv0, const float* __restrict__ bv1,
    const float* __restrict__ bv2, const float* __restrict__ bv3,
    const float* __restrict__ bv4,
    int d, int m0, int j0, unsigned char* lds)
{
  const int tid = threadIdx.x;
  const int w = tid >> 6;
  const int l = tid & 63;
  const int l15 = l & 15;
  const int quad = l >> 4;
  const int q8 = quad * 8;
  const int mh = w & 1, jh = w >> 1;
  const int n = 1 << d;
  const int jfb = j0 >> 4;
  constexpr int NKT = LEAF ? 4 : 12;   // BK=32 k-steps
  constexpr int NBC = LEAF ? 3 : 5;    // B chunks staged per wave per step

  // staging lane's A row: m0 + w*16 + l15 (wave w stages A chunk w)
  const int ms = m0 + w * 16 + l15;
  const int bs = ms >> d;
  const int ids = ms & (n - 1);
  const float* xrow = x + ((size_t)bs * NTOT + (n - 1) + ids) * HDIM;
  const __bf16* hrow = LEAF ? (const __bf16*)nullptr
                            : h_prev + ((size_t)bs * 2 * n + 2 * ids) * HDIM;

  auto stage = [&](int ks) {
    unsigned char* Ab = lds + (ks & 1) * 24576;
    unsigned char* Bb = Ab + 4096;
#pragma unroll
    for (int q = 0; q < NBC; ++q) {
      int c = w * NBC + q;
      int g;
      if (LEAF) { const int gm[3] = {0, 3, 4}; g = gm[c >> 2]; }
      else g = c >> 2;
      int jfl = c & 3;
      const __bf16* s = PW + (((size_t)(g * 8 + jfb + jfl) * 12 + ks) * 64 + l) * 8;
      load_lds16(s, Bb + (g * 4 + jfl) * 1024);
    }
    if (LEAF || ks < 4) {
      const float* s = xrow + ks * 32 + q8;
      float4 v0 = *(const float4*)s;
      float4 v1 = *(const float4*)(s + 4);
      bf16x8 wv;
      wv[0] = (__bf16)v0.x; wv[1] = (__bf16)v0.y; wv[2] = (__bf16)v0.z; wv[3] = (__bf16)v0.w;
      wv[4] = (__bf16)v1.x; wv[5] = (__bf16)v1.y; wv[6] = (__bf16)v1.z; wv[7] = (__bf16)v1.w;
      *(bf16x8*)(Ab + w * 1024 + l * 16) = wv;
    } else {
      int off = (ks < 8) ? (ks - 4) * 32 : 128 + (ks - 8) * 32;
      load_lds16(hrow + off + q8, Ab + w * 1024);
    }
  };

  f32x4 acc[2][2][5];
#pragma unroll
  for (int mf = 0; mf < 2; ++mf)
#pragma unroll
    for (int jfl = 0; jfl < 2; ++jfl)
#pragma unroll
      for (int g = 0; g < 5; ++g)
        acc[mf][jfl][g] = (f32x4){0.f, 0.f, 0.f, 0.f};

  stage(0);
  for (int ks = 0; ks < NKT; ++ks) {
    __syncthreads();                     // buf ks&1 staged; other buf free
    if (ks + 1 < NKT) stage(ks + 1);
    const unsigned char* Ab = lds + (ks & 1) * 24576;
    const unsigned char* Bb = Ab + 4096;
    bf16x8 a0 = *(const bf16x8*)(Ab + (mh * 2 + 0) * 1024 + l * 16);
    bf16x8 a1 = *(const bf16x8*)(Ab + (mh * 2 + 1) * 1024 + l * 16);
#pragma unroll
    for (int g = 0; g < 5; ++g) {
      if (LEAF && (g == 1 || g == 2)) continue;   // children zero -> fl/fr unused
#pragma unroll
      for (int jfl = 0; jfl < 2; ++jfl) {
        bf16x8 bb = *(const bf16x8*)(Bb + (g * 4 + jh * 2 + jfl) * 1024 + l * 16);
        acc[0][jfl][g] = __builtin_amdgcn_mfma_f32_16x16x32_bf16(a0, bb, acc[0][jfl][g], 0, 0, 0);
        acc[1][jfl][g] = __builtin_amdgcn_mfma_f32_16x16x32_bf16(a1, bb, acc[1][jfl][g], 0, 0, 0);
      }
    }
  }

  // epilogue: D layout col(j)=lane&15, row(m)=quad*4+r  (verified R1)
#pragma unroll
  for (int jfl = 0; jfl < 2; ++jfl) {
    const int je = j0 + jh * 32 + jfl * 16 + l15;
    const float b0 = bv0[je], b1 = bv1[je], b2 = bv2[je], b3 = bv3[je], b4 = bv4[je];
#pragma unroll
    for (int mf = 0; mf < 2; ++mf) {
#pragma unroll
      for (int r = 0; r < 4; ++r) {
        int me = m0 + mh * 32 + mf * 16 + quad * 4 + r;
        int b = me >> d;
        int id = me & (n - 1);
        float gi = sigmoid_f(acc[mf][jfl][0][r] + b0);
        float go = sigmoid_f(acc[mf][jfl][3][r] + b3);
        float gu = tanh_f(acc[mf][jfl][4][r] + b4);
        float cv = gi * gu;
        if (!LEAF) {
          float gl = sigmoid_f(acc[mf][jfl][1][r] + b1);
          float gr = sigmoid_f(acc[mf][jfl][2][r] + b2);
          size_t cbase = ((size_t)b * 2 * n + 2 * id) * HDIM + je;
          cv += gl * c_prev[cbase] + gr * c_prev[cbase + HDIM];
        }
        size_t ob = ((size_t)b * n + id) * HDIM + je;
        c_out[ob] = cv;
        h_out[ob] = (__bf16)(go * tanh_f(cv));
      }
    }
  }
}

template<bool LEAF>
__global__ __launch_bounds__(256, 2) void level_kernel(
    const float* __restrict__ x, const __bf16* __restrict__ PW,
    const float* __restrict__ bv0, const float* __restrict__ bv1,
    const float* __restrict__ bv2, const float* __restrict__ bv3,
    const float* __restrict__ bv4,
    const __bf16* __restrict__ h_prev, const float* __restrict__ c_prev,
    __bf16* __restrict__ h_out, float* __restrict__ c_out, int d)
{
  __shared__ unsigned char lds[49152];
  tile_body<LEAF>(x, PW, h_prev, c_prev, h_out, c_out,
                  bv0, bv1, bv2, bv3, bv4, d,
                  (int)blockIdx.x * 64, (int)blockIdx.y * 64, lds);
}

// ---------------------------------------------------------------------------
// Tail: one block per batch element, levels d=5..0 + classifier, no grid sync.
// LDS map (157184 B total, 1 block/CU):
//   [0,       81920)  B staging double-buffer: 2 x 40 chunks x 1KB (full j=128)
//   [81920,  132096)  P: h 64x[256B swizzled] (16384) + c 64x132 f32 (33792)
//   [132096, 157184)  Q: h 32x[256B swizzled] ( 8192) + c 32x132 f32 (16896)
// h swizzle: byte = node*256 + ((2*col) ^ ((node&7)<<4))  (G4 XOR fix; read &
// write sides use the same involution). c stride 132 floats -> 2-way banks.
// ---------------------------------------------------------------------------
#define TB_P  81920
#define TB_Q  132096
#define CSTR  132

__global__ __launch_bounds__(256, 1) void tail_kernel(
    const float* __restrict__ x, const __bf16* __restrict__ PW,
    const float* __restrict__ bv0, const float* __restrict__ bv1,
    const float* __restrict__ bv2, const float* __restrict__ bv3,
    const float* __restrict__ bv4,
    const float* __restrict__ Wcls, const float* __restrict__ bcls,
    const __bf16* __restrict__ h6, const float* __restrict__ c6,
    float* __restrict__ out)
{
  __shared__ unsigned char lds[157184];
  const int b = blockIdx.x;
  const int tid = threadIdx.x;
  const int w = tid >> 6;
  const int l = tid & 63;
  const int l15 = l & 15;
  const int quad = l >> 4;
  const int q8 = quad * 8;

  unsigned char* Ph = lds + TB_P;
  float* Pc = (float*)(lds + TB_P + 16384);
  unsigned char* Qh = lds + TB_Q;
  float* Qc = (float*)(lds + TB_Q + 8192);

  // ---- load level-6 h/c (written by level_kernel d=6) into P ----
  {
    const __bf16* hs = h6 + (size_t)b * 64 * HDIM;
#pragma unroll
    for (int it = 0; it < 4; ++it) {
      int idx = it * 256 + tid;              // 1024 = 64 nodes x 16 chunks
      int node = idx >> 4, i8 = idx & 15;
      bf16x8 v = *(const bf16x8*)(hs + node * HDIM + i8 * 8);
      *(bf16x8*)(Ph + node * 256 + ((i8 * 16) ^ ((node & 7) << 4))) = v;
    }
    const float* cs = c6 + (size_t)b * 64 * HDIM;
#pragma unroll
    for (int it = 0; it < 8; ++it) {
      int idx = it * 256 + tid;              // 2048 = 64 nodes x 32 float4
      int node = idx >> 5, seg = idx & 31;
      float4 v = *(const float4*)(cs + node * HDIM + seg * 4);
      *(float4*)(Pc + node * CSTR + seg * 4) = v;
    }
  }

  for (int d = 5; d >= 0; --d) {
    const int s = 5 - d;
    const int n = 1 << d;
    const int nmf = (d == 5) ? 2 : 1;        // m-frags (M = n, padded to 16)
    unsigned char* prev_h = (s & 1) ? Qh : Ph;
    float*         prev_c = (s & 1) ? Qc : Pc;
    unsigned char* cur_h  = (s & 1) ? Ph : Qh;
    float*         cur_c  = (s & 1) ? Pc : Qc;

    // hoist x-part A-frags (k=0..127) into registers: no global latency in k-loop.
    // rows beyond n are in-bounds garbage; discarded by me<n in the epilogue.
    bf16x8 xf[2][4];
#pragma unroll
    for (int mf = 0; mf < 2; ++mf) {
      const float* xr = x + ((size_t)b * NTOT + (n - 1) + mf * 16 + l15) * HDIM + q8;
#pragma unroll
      for (int ks = 0; ks < 4; ++ks) {
        float4 v0 = *(const float4*)(xr + ks * 32);
        float4 v1 = *(const float4*)(xr + ks * 32 + 4);
        bf16x8 t;
        t[0] = (__bf16)v0.x; t[1] = (__bf16)v0.y; t[2] = (__bf16)v0.z; t[3] = (__bf16)v0.w;
        t[4] = (__bf16)v1.x; t[5] = (__bf16)v1.y; t[6] = (__bf16)v1.z; t[7] = (__bf16)v1.w;
        xf[mf][ks] = t;
      }
    }

    auto stageB = [&](int ks) {
      unsigned char* Bb = lds + (ks & 1) * 40960;
#pragma unroll
      for (int q = 0; q < 10; ++q) {
        int c = w * 10 + q;                  // chunk = g*8 + jf, c in [0,40)
        const __bf16* src = PW + ((size_t)(c * 12 + ks) * 64 + l) * 8;
        load_lds16(src, Bb + c * 1024);      // wave-uniform dest + lane*16 (HW)
      }
    };

    f32x4 acc[2][2][5];
#pragma unroll
    for (int mf = 0; mf < 2; ++mf)
#pragma unroll
      for (int jfl = 0; jfl < 2; ++jfl)
#pragma unroll
        for (int g = 0; g < 5; ++g)
          acc[mf][jfl][g] = (f32x4){0.f, 0.f, 0.f, 0.f};

    stageB(0);
    for (int ks = 0; ks < 12; ++ks) {
      __syncthreads();   // drains stage(ks); at ks=0 also fences prev h/c LDS writes
      if (ks < 11) stageB(ks + 1);
      const unsigned char* Bb = lds + (ks & 1) * 40960;
      bf16x8 a0, a1;
      if (ks < 4) {
        a0 = xf[0][ks];
        a1 = xf[1][ks];
      } else {
        const int o = (ks < 8) ? 0 : 1;                    // hl : hr child
        const int col2 = (((ks - (o ? 8 : 4)) * 32) + q8) * 2;
        int n0 = 2 * l15 + o;
        int n1 = 2 * (16 + l15) + o;
        a0 = *(const bf16x8*)(prev_h + n0 * 256 + (col2 ^ ((n0 & 7) << 4)));
        a1 = *(const bf16x8*)(prev_h + n1 * 256 + (col2 ^ ((n1 & 7) << 4)));
      }
#pragma unroll
      for (int g = 0; g < 5; ++g) {
#pragma unroll
        for (int jfl = 0; jfl < 2; ++jfl) {
          bf16x8 bb = *(const bf16x8*)(Bb + (g * 8 + w * 2 + jfl) * 1024 + l * 16);
          acc[0][jfl][g] = __builtin_amdgcn_mfma_f32_16x16x32_bf16(a0, bb, acc[0][jfl][g], 0, 0, 0);
          if (nmf == 2)
            acc[1][jfl][g] = __builtin_amdgcn_mfma_f32_16x16x32_bf16(a1, bb, acc[1][jfl][g], 0, 0, 0);
        }
      }
    }

    // epilogue -> cur LDS buffers (D layout: col=l15, row=quad*4+r)
#pragma unroll
    for (int jfl = 0; jfl < 2; ++jfl) {
      const int je = w * 32 + jfl * 16 + l15;
      const float b0 = bv0[je], b1 = bv1[je], b2 = bv2[je], b3 = bv3[je], b4 = bv4[je];
#pragma unroll
      for (int mf = 0; mf < 2; ++mf) {
#pragma unroll
        for (int r = 0; r < 4; ++r) {
          const int me = mf * 16 + quad * 4 + r;
          if (me < n) {
            float gi = sigmoid_f(acc[mf][jfl][0][r] + b0);
            float gl = sigmoid_f(acc[mf][jfl][1][r] + b1);
            float gr = sigmoid_f(acc[mf][jfl][2][r] + b2);
            float go = sigmoid_f(acc[mf][jfl][3][r] + b3);
            float gu = tanh_f(acc[mf][jfl][4][r] + b4);
            float cv = gi * gu + gl * prev_c[(2 * me) * CSTR + je]
                               + gr * prev_c[(2 * me + 1) * CSTR + je];
            cur_c[me * CSTR + je] = cv;
            *(__bf16*)(cur_h + me * 256 + ((je * 2) ^ ((me & 7) << 4))) =
                (__bf16)(go * tanh_f(cv));
          }
        }
      }
    }
    // next level's ks=0 barrier fences these LDS writes before they're read
  }

  // classifier: root h = P.h node 0 (d=0 wrote cur=P); node 0 is unswizzled
  __syncthreads();
  if (tid < NCLS) {
    float sacc = bcls[tid];
    for (int k = 0; k < HDIM; ++k)
      sacc += (float)(*(const __bf16*)(Ph + k * 2)) * Wcls[tid * HDIM + k];
    out[(size_t)b * NCLS + tid] = sacc;
  }
}

extern "C" void kernel_launch(void* const* d_in, const int* in_sizes, int n_in,
                              void* d_out, int out_size, void* d_ws, size_t ws_size,
                              hipStream_t stream) {
  const float* x  = (const float*)d_in[0];
  const float* W[5]  = {(const float*)d_in[1], (const float*)d_in[3], (const float*)d_in[5],
                        (const float*)d_in[7], (const float*)d_in[9]};
  const float* bv[5] = {(const float*)d_in[2], (const float*)d_in[4], (const float*)d_in[6],
                        (const float*)d_in[8], (const float*)d_in[10]};
  const float* Wcls = (const float*)d_in[11];
  const float* bcls = (const float*)d_in[12];

  uint8_t* ws = (uint8_t*)d_ws;
  __bf16* hb0 = (__bf16*)ws;                       // 32 MiB (d = 9,7)
  __bf16* hb1 = (__bf16*)(ws + 33554432);          // 16 MiB (d = 8,6)
  float*  cb0 = (float*)(ws + 50331648);           // 64 MiB
  float*  cb1 = (float*)(ws + 117440512);          // 32 MiB
  __bf16* PW  = (__bf16*)(ws + 150994944);         // 480 KB frag-packed weights

  pack_w<<<120, 256, 0, stream>>>(W[0], W[1], W[2], W[3], W[4], PW);

  // leaf d=9 -> hb0/cb0
  level_kernel<true><<<dim3(2048, 2), 256, 0, stream>>>(
      x, PW, bv[0], bv[1], bv[2], bv[3], bv[4], hb1, cb1, hb0, cb0, 9);
  // d=8..6
  for (int d = 8; d >= 6; --d) {
    const int p = 9 - d;
    __bf16* h_out = (p & 1) ? hb1 : hb0;
    float*  c_out = (p & 1) ? cb1 : cb0;
    const __bf16* h_prev = (p & 1) ? hb0 : hb1;
    const float*  c_prev = (p & 1) ? cb0 : cb1;
    dim3 grid((BATCH << d) >> 6, 2);
    level_kernel<false><<<grid, 256, 0, stream>>>(
        x, PW, bv[0], bv[1], bv[2], bv[3], bv[4], h_prev, c_prev, h_out, c_out, d);
  }
  // d=5..0 + classifier: batch-local blocks, no grid barriers (d=6 out = hb1/cb1)
  tail_kernel<<<BATCH, 256, 0, stream>>>(
      x, PW, bv[0], bv[1], bv[2], bv[3], bv[4],
      Wcls, bcls, hb1, cb1, (float*)d_out);
}